// Round 1
// baseline (430.290 us; speedup 1.0000x reference)
//
#include <hip/hip_runtime.h>
#include <math.h>

// DifferentiableRenderer: B=2 cameras, N=65536 gaussians, 128x128 image.
// Pipeline: proj (fold constants, cull radius) -> zero accum -> tiled
// gaussian accumulation (LDS-staged, wave-uniform cull, 8 px/thread) ->
// finalize (num / (den + nchunks*EPS)).

#define HH 128
#define WW 128
#define HWP (HH * WW)
#define TILE_ROWS 16
#define PPT 8            // pixels per thread (one column, stride 2 rows)
#define GSPLIT 64        // gaussian splits (blocks per tile)
#define CHUNK_G 256      // gaussians staged in LDS per chunk

__global__ void proj_kernel(const float* __restrict__ pos,
                            const float* __restrict__ col,
                            const float* __restrict__ opa,
                            const float* __restrict__ scl,
                            const float* __restrict__ qv,
                            const float* __restrict__ tv,
                            const float* fxp, const float* fyp,
                            const float* cxp, const float* cyp,
                            float4* __restrict__ out, int N, int B) {
    int i = blockIdx.x * blockDim.x + threadIdx.x;
    if (i >= N * B) return;
    int b = i / N;
    int g = i - b * N;

    float qw = qv[b * 4 + 0], qx = qv[b * 4 + 1], qy = qv[b * 4 + 2], qz = qv[b * 4 + 3];
    float qn = rsqrtf(qw * qw + qx * qx + qy * qy + qz * qz);
    qw *= qn; qx *= qn; qy *= qn; qz *= qn;
    float r00 = 1.0f - 2.0f * (qy * qy + qz * qz);
    float r01 = 2.0f * (qx * qy - qz * qw);
    float r02 = 2.0f * (qx * qz + qy * qw);
    float r10 = 2.0f * (qx * qy + qz * qw);
    float r11 = 1.0f - 2.0f * (qx * qx + qz * qz);
    float r12 = 2.0f * (qy * qz - qx * qw);
    float r20 = 2.0f * (qx * qz - qy * qw);
    float r21 = 2.0f * (qy * qz + qx * qw);
    float r22 = 1.0f - 2.0f * (qx * qx + qy * qy);

    float X = pos[g * 3 + 0], Y = pos[g * 3 + 1], Z = pos[g * 3 + 2];
    float pcx = r00 * X + r01 * Y + r02 * Z + tv[b * 3 + 0];
    float pcy = r10 * X + r11 * Y + r12 * Z + tv[b * 3 + 1];
    float pcz = r20 * X + r21 * Y + r22 * Z + tv[b * 3 + 2];

    float px = pcx / pcz * (*fxp) + (*cxp);
    float py = pcy / pcz * (*fyp) + (*cyp);

    float s = scl[g];
    float var = s * s;
    float c = -0.72134752044448170f / var;          // -0.5 * log2(e) / var
    float l = __builtin_amdgcn_logf(opa[g]);        // log2(opacity)
    // cull radius: keep terms with w >= 2^-60  (d2 <= (60+l)*var*2ln2)
    float d2max = fmaxf(60.0f + l, 0.0f) * var * 1.38629436111989061f;
    float rad = sqrtf(d2max);

    out[(size_t)(b * N + g) * 2 + 0] = make_float4(px, py, c, rad);
    out[(size_t)(b * N + g) * 2 + 1] = make_float4(col[g * 3 + 0], col[g * 3 + 1], col[g * 3 + 2], l);
}

__global__ void zero_kernel(float* __restrict__ p, int n) {
    int i = blockIdx.x * blockDim.x + threadIdx.x;
    if (i < n) p[i] = 0.0f;
}

__global__ __launch_bounds__(256) void accum_kernel(const float4* __restrict__ gdata,
                                                    float* __restrict__ accbuf,
                                                    int N, int gpb) {
    __shared__ float4 sh[CHUNK_G * 2];
    int tile = blockIdx.x;          // 8 row-tiles of 16 rows
    int gs   = blockIdx.y;          // gaussian split
    int b    = blockIdx.z;          // camera
    int tid  = threadIdx.x;
    int x    = tid & 127;
    int yrow = tid >> 7;            // 0 or 1
    int ytop = tile * TILE_ROWS;

    float xf  = (float)x;
    float ylo = (float)ytop;
    float yhi = (float)(ytop + TILE_ROWS - 1);

    float nr[PPT], ng[PPT], nb[PPT], nd[PPT];
#pragma unroll
    for (int p = 0; p < PPT; ++p) { nr[p] = 0.0f; ng[p] = 0.0f; nb[p] = 0.0f; nd[p] = 0.0f; }

    const float4* gbase = gdata + (size_t)b * N * 2;
    int g0 = gs * gpb;

    for (int cb = 0; cb < gpb; cb += CHUNK_G) {
        int src = (g0 + cb) * 2;
        sh[tid]       = gbase[src + tid];
        sh[tid + 256] = gbase[src + 256 + tid];
        __syncthreads();

        for (int j = 0; j < CHUNK_G; ++j) {
            float4 f0 = sh[j * 2];   // px, py, c, rad  (wave-uniform broadcast)
            float px = f0.x, py = f0.y, c = f0.z, rad = f0.w;
            // wave-uniform cull: whole gaussian outside this 128x16 tile band
            if (py + rad < ylo || py - rad > yhi || px + rad < 0.0f || px - rad > 127.0f)
                continue;
            float4 f1 = sh[j * 2 + 1];  // cr, cg, cb, l
            float dx  = px - xf;
            float dx2 = dx * dx;
            float dy  = py - (float)(ytop + yrow);
#pragma unroll
            for (int p = 0; p < PPT; ++p) {
                float t = __builtin_fmaf(dy, dy, dx2);
                float a = __builtin_fmaf(t, c, f1.w);
                float w = __builtin_amdgcn_exp2f(a);
                nr[p] = __builtin_fmaf(w, f1.x, nr[p]);
                ng[p] = __builtin_fmaf(w, f1.y, ng[p]);
                nb[p] = __builtin_fmaf(w, f1.z, nb[p]);
                nd[p] += w;
                dy -= 2.0f;
            }
        }
        __syncthreads();
    }

    float* ab = accbuf + (size_t)b * HWP * 4;
#pragma unroll
    for (int p = 0; p < PPT; ++p) {
        int y = ytop + yrow + p * 2;
        int pix = y * WW + x;
        atomicAdd(ab + pix * 4 + 0, nr[p]);
        atomicAdd(ab + pix * 4 + 1, ng[p]);
        atomicAdd(ab + pix * 4 + 2, nb[p]);
        atomicAdd(ab + pix * 4 + 3, nd[p]);
    }
}

__global__ void final_kernel(const float* __restrict__ accbuf,
                             float* __restrict__ out, int B, float epsadd) {
    int i = blockIdx.x * blockDim.x + threadIdx.x;   // over B*HW
    if (i >= B * HWP) return;
    int b = i / HWP;
    int p = i - b * HWP;
    const float* a = accbuf + (size_t)i * 4;
    float den = fmaxf(a[3] + epsadd, 1e-8f);
    out[(size_t)(b * 3 + 0) * HWP + p] = a[0] / den;
    out[(size_t)(b * 3 + 1) * HWP + p] = a[1] / den;
    out[(size_t)(b * 3 + 2) * HWP + p] = a[2] / den;
}

extern "C" void kernel_launch(void* const* d_in, const int* in_sizes, int n_in,
                              void* d_out, int out_size, void* d_ws, size_t ws_size,
                              hipStream_t stream) {
    const float* pos = (const float*)d_in[0];
    const float* col = (const float*)d_in[1];
    const float* opa = (const float*)d_in[2];
    const float* scl = (const float*)d_in[3];
    const float* qv  = (const float*)d_in[4];
    const float* tv  = (const float*)d_in[5];
    const float* fx  = (const float*)d_in[6];
    const float* fy  = (const float*)d_in[7];
    const float* cx  = (const float*)d_in[8];
    const float* cy  = (const float*)d_in[9];

    int N = in_sizes[0] / 3;
    int B = in_sizes[4] / 4;

    float4* proj   = (float4*)d_ws;
    float*  accbuf = (float*)((char*)d_ws + (size_t)B * N * 2 * sizeof(float4));
    float*  outp   = (float*)d_out;

    int tot = N * B;
    proj_kernel<<<(tot + 255) / 256, 256, 0, stream>>>(pos, col, opa, scl, qv, tv,
                                                       fx, fy, cx, cy, proj, N, B);

    int accn = B * HWP * 4;
    zero_kernel<<<(accn + 255) / 256, 256, 0, stream>>>(accbuf, accn);

    int gpb = N / GSPLIT;   // 1024 gaussians per block (N=65536)
    dim3 grid(HH / TILE_ROWS, GSPLIT, B);
    accum_kernel<<<grid, 256, 0, stream>>>(proj, accbuf, N, gpb);

    float epsadd = (float)(N / 2048) * 1e-8f;  // reference adds EPS once per 2048-chunk
    final_kernel<<<(B * HWP + 255) / 256, 256, 0, stream>>>(accbuf, outp, B, epsadd);
}

// Round 2
// 362.961 us; speedup vs baseline: 1.1855x; 1.1855x over previous
//
#include <hip/hip_runtime.h>
#include <math.h>

// DifferentiableRenderer: B=2 cameras, N=65536 gaussians, 128x128 image.
// R2: thread-parallel cull + ballot/compact into LDS -> branch-free dense
// inner loop; GSPLIT 64->128 for full 32-wave/CU occupancy; cull thr 2^-45.

#define HH 128
#define WW 128
#define HWP (HH * WW)
#define TILE_ROWS 16
#define PPT 8            // pixels per thread (one column, stride 2 rows)
#define GSPLIT 128       // gaussian splits (blocks per tile)
#define CHUNK_G 256      // gaussians culled/compacted per chunk

__global__ void proj_kernel(const float* __restrict__ pos,
                            const float* __restrict__ col,
                            const float* __restrict__ opa,
                            const float* __restrict__ scl,
                            const float* __restrict__ qv,
                            const float* __restrict__ tv,
                            const float* fxp, const float* fyp,
                            const float* cxp, const float* cyp,
                            float4* __restrict__ out, int N, int B) {
    int i = blockIdx.x * blockDim.x + threadIdx.x;
    if (i >= N * B) return;
    int b = i / N;
    int g = i - b * N;

    float qw = qv[b * 4 + 0], qx = qv[b * 4 + 1], qy = qv[b * 4 + 2], qz = qv[b * 4 + 3];
    float qn = rsqrtf(qw * qw + qx * qx + qy * qy + qz * qz);
    qw *= qn; qx *= qn; qy *= qn; qz *= qn;
    float r00 = 1.0f - 2.0f * (qy * qy + qz * qz);
    float r01 = 2.0f * (qx * qy - qz * qw);
    float r02 = 2.0f * (qx * qz + qy * qw);
    float r10 = 2.0f * (qx * qy + qz * qw);
    float r11 = 1.0f - 2.0f * (qx * qx + qz * qz);
    float r12 = 2.0f * (qy * qz - qx * qw);
    float r20 = 2.0f * (qx * qz - qy * qw);
    float r21 = 2.0f * (qy * qz + qx * qw);
    float r22 = 1.0f - 2.0f * (qx * qx + qy * qy);

    float X = pos[g * 3 + 0], Y = pos[g * 3 + 1], Z = pos[g * 3 + 2];
    float pcx = r00 * X + r01 * Y + r02 * Z + tv[b * 3 + 0];
    float pcy = r10 * X + r11 * Y + r12 * Z + tv[b * 3 + 1];
    float pcz = r20 * X + r21 * Y + r22 * Z + tv[b * 3 + 2];

    float px = pcx / pcz * (*fxp) + (*cxp);
    float py = pcy / pcz * (*fyp) + (*cyp);

    float s = scl[g];
    float var = s * s;
    float c = -0.72134752044448170f / var;          // -0.5 * log2(e) / var
    float l = __builtin_amdgcn_logf(opa[g]);        // log2(opacity)
    // cull radius: keep terms with w >= 2^-45  (d2 <= (45+l)*var*2ln2)
    float d2max = fmaxf(45.0f + l, 0.0f) * var * 1.38629436111989061f;
    float rad = sqrtf(d2max);

    out[(size_t)(b * N + g) * 2 + 0] = make_float4(px, py, c, rad);
    out[(size_t)(b * N + g) * 2 + 1] = make_float4(col[g * 3 + 0], col[g * 3 + 1], col[g * 3 + 2], l);
}

__global__ void zero_kernel(float* __restrict__ p, int n) {
    int i = blockIdx.x * blockDim.x + threadIdx.x;
    if (i < n) p[i] = 0.0f;
}

__global__ __launch_bounds__(256) void accum_kernel(const float4* __restrict__ gdata,
                                                    float* __restrict__ accbuf,
                                                    int N, int gpb) {
    __shared__ float4 shc[CHUNK_G * 2];   // compacted survivors: (px,py,c,l),(r,g,b,-)
    __shared__ int wcnt[4];
    int tile = blockIdx.x;          // 8 row-tiles of 16 rows
    int gs   = blockIdx.y;          // gaussian split
    int b    = blockIdx.z;          // camera
    int tid  = threadIdx.x;
    int x    = tid & 127;
    int yrow = tid >> 7;            // 0 or 1
    int ytop = tile * TILE_ROWS;
    int wid  = tid >> 6;
    int lane = tid & 63;

    float xf  = (float)x;
    float ylo = (float)ytop;
    float yhi = (float)(ytop + TILE_ROWS - 1);
    float y0f = (float)(ytop + yrow);

    float nr[PPT], ng[PPT], nb[PPT], nd[PPT];
#pragma unroll
    for (int p = 0; p < PPT; ++p) { nr[p] = 0.0f; ng[p] = 0.0f; nb[p] = 0.0f; nd[p] = 0.0f; }

    const float4* gbase = gdata + (size_t)b * N * 2;
    int g0 = gs * gpb;

    for (int cb = 0; cb < gpb; cb += CHUNK_G) {
        // ---- thread-parallel cull: one gaussian per thread (coalesced 32B) ----
        int src = (g0 + cb + tid) * 2;
        float4 f0 = gbase[src];        // px, py, c, rad
        float4 f1 = gbase[src + 1];    // r, g, b, l
        float px = f0.x, py = f0.y, rad = f0.w;
        bool keep = (py + rad >= ylo) & (py - rad <= yhi) &
                    (px + rad >= 0.0f) & (px - rad <= 127.0f);
        unsigned long long m = __ballot(keep);

        __syncthreads();                       // prior dense loop done with shc/wcnt
        if (lane == 0) wcnt[wid] = __popcll(m);
        __syncthreads();                       // wcnt visible
        int base = 0;
        if (wid > 0) base += wcnt[0];
        if (wid > 1) base += wcnt[1];
        if (wid > 2) base += wcnt[2];
        int total = wcnt[0] + wcnt[1] + wcnt[2] + wcnt[3];
        int pos = base + __popcll(m & ((1ull << lane) - 1ull));
        if (keep) {
            shc[pos * 2]     = make_float4(f0.x, f0.y, f0.z, f1.w);  // px,py,c,l
            shc[pos * 2 + 1] = f1;                                    // r,g,b,-
        }
        __syncthreads();                       // shc visible

        // ---- branch-free dense loop over survivors (broadcast LDS reads) ----
        for (int j = 0; j < total; ++j) {
            float4 a0 = shc[j * 2];
            float4 a1 = shc[j * 2 + 1];
            float dxx = a0.x - xf;
            float dx2 = dxx * dxx;
            float dy  = a0.y - y0f;
#pragma unroll
            for (int p = 0; p < PPT; ++p) {
                float t = __builtin_fmaf(dy, dy, dx2);
                float e = __builtin_fmaf(t, a0.z, a0.w);
                float w = __builtin_amdgcn_exp2f(e);
                nr[p] = __builtin_fmaf(w, a1.x, nr[p]);
                ng[p] = __builtin_fmaf(w, a1.y, ng[p]);
                nb[p] = __builtin_fmaf(w, a1.z, nb[p]);
                nd[p] += w;
                dy -= 2.0f;
            }
        }
    }

    float* ab = accbuf + (size_t)b * HWP * 4;
#pragma unroll
    for (int p = 0; p < PPT; ++p) {
        int y = ytop + yrow + p * 2;
        int pix = y * WW + x;
        atomicAdd(ab + pix * 4 + 0, nr[p]);
        atomicAdd(ab + pix * 4 + 1, ng[p]);
        atomicAdd(ab + pix * 4 + 2, nb[p]);
        atomicAdd(ab + pix * 4 + 3, nd[p]);
    }
}

__global__ void final_kernel(const float* __restrict__ accbuf,
                             float* __restrict__ out, int B, float epsadd) {
    int i = blockIdx.x * blockDim.x + threadIdx.x;   // over B*HW
    if (i >= B * HWP) return;
    int b = i / HWP;
    int p = i - b * HWP;
    const float* a = accbuf + (size_t)i * 4;
    float den = fmaxf(a[3] + epsadd, 1e-8f);
    out[(size_t)(b * 3 + 0) * HWP + p] = a[0] / den;
    out[(size_t)(b * 3 + 1) * HWP + p] = a[1] / den;
    out[(size_t)(b * 3 + 2) * HWP + p] = a[2] / den;
}

extern "C" void kernel_launch(void* const* d_in, const int* in_sizes, int n_in,
                              void* d_out, int out_size, void* d_ws, size_t ws_size,
                              hipStream_t stream) {
    const float* pos = (const float*)d_in[0];
    const float* col = (const float*)d_in[1];
    const float* opa = (const float*)d_in[2];
    const float* scl = (const float*)d_in[3];
    const float* qv  = (const float*)d_in[4];
    const float* tv  = (const float*)d_in[5];
    const float* fx  = (const float*)d_in[6];
    const float* fy  = (const float*)d_in[7];
    const float* cx  = (const float*)d_in[8];
    const float* cy  = (const float*)d_in[9];

    int N = in_sizes[0] / 3;
    int B = in_sizes[4] / 4;

    float4* proj   = (float4*)d_ws;
    float*  accbuf = (float*)((char*)d_ws + (size_t)B * N * 2 * sizeof(float4));
    float*  outp   = (float*)d_out;

    int tot = N * B;
    proj_kernel<<<(tot + 255) / 256, 256, 0, stream>>>(pos, col, opa, scl, qv, tv,
                                                       fx, fy, cx, cy, proj, N, B);

    int accn = B * HWP * 4;
    zero_kernel<<<(accn + 255) / 256, 256, 0, stream>>>(accbuf, accn);

    int gpb = N / GSPLIT;   // 512 gaussians per block (N=65536)
    dim3 grid(HH / TILE_ROWS, GSPLIT, B);
    accum_kernel<<<grid, 256, 0, stream>>>(proj, accbuf, N, gpb);

    float epsadd = (float)(N / 2048) * 1e-8f;  // reference adds EPS once per 2048-chunk
    final_kernel<<<(B * HWP + 255) / 256, 256, 0, stream>>>(accbuf, outp, B, epsadd);
}

// Round 4
// 330.283 us; speedup vs baseline: 1.3028x; 1.0989x over previous
//
#include <hip/hip_runtime.h>
#include <math.h>

// DifferentiableRenderer: B=2 cameras, N=65536 gaussians, 128x128 image.
// R4 = R2 structure (separate zero kernel, known-good) + two levers from R3:
//   - XCD balance: grid.x = GSPLIT (linear%8 = gs%8, statistically even)
//   - prescaled coords: 6 VALU + 1 exp2 per pixel

#define HH 128
#define WW 128
#define HWP (HH * WW)
#define TILE_ROWS 16
#define PPT 8            // pixels per thread (one column, stride 2 rows)
#define GSPLIT 128       // gaussian splits (blocks per tile)
#define CHUNK_G 256      // gaussians culled/compacted per chunk

__global__ void proj_kernel(const float* __restrict__ pos,
                            const float* __restrict__ col,
                            const float* __restrict__ opa,
                            const float* __restrict__ scl,
                            const float* __restrict__ qv,
                            const float* __restrict__ tv,
                            const float* fxp, const float* fyp,
                            const float* cxp, const float* cyp,
                            float4* __restrict__ out, int N, int B) {
    int i = blockIdx.x * blockDim.x + threadIdx.x;
    if (i >= N * B) return;
    int b = i / N;
    int g = i - b * N;

    float qw = qv[b * 4 + 0], qx = qv[b * 4 + 1], qy = qv[b * 4 + 2], qz = qv[b * 4 + 3];
    float qn = rsqrtf(qw * qw + qx * qx + qy * qy + qz * qz);
    qw *= qn; qx *= qn; qy *= qn; qz *= qn;
    float r00 = 1.0f - 2.0f * (qy * qy + qz * qz);
    float r01 = 2.0f * (qx * qy - qz * qw);
    float r02 = 2.0f * (qx * qz + qy * qw);
    float r10 = 2.0f * (qx * qy + qz * qw);
    float r11 = 1.0f - 2.0f * (qx * qx + qz * qz);
    float r12 = 2.0f * (qy * qz - qx * qw);
    float r20 = 2.0f * (qx * qz - qy * qw);
    float r21 = 2.0f * (qy * qz + qx * qw);
    float r22 = 1.0f - 2.0f * (qx * qx + qy * qy);

    float X = pos[g * 3 + 0], Y = pos[g * 3 + 1], Z = pos[g * 3 + 2];
    float pcx = r00 * X + r01 * Y + r02 * Z + tv[b * 3 + 0];
    float pcy = r10 * X + r11 * Y + r12 * Z + tv[b * 3 + 1];
    float pcz = r20 * X + r21 * Y + r22 * Z + tv[b * 3 + 2];

    float px = pcx / pcz * (*fxp) + (*cxp);
    float py = pcy / pcz * (*fyp) + (*cyp);

    float sc = scl[g];
    float var = sc * sc;
    float l = __builtin_amdgcn_logf(opa[g]);        // log2(opacity)
    // w = op*exp(-0.5*d2/var) = exp2(l - (s*dx)^2 - (s*dy)^2), s = sqrt(0.5*log2e)/scale
    float s = 0.84932180028801905f / sc;
    // cull radius: keep terms with w >= 2^-45  (d2 <= (45+l)*var*2ln2)
    float d2max = fmaxf(45.0f + l, 0.0f) * var * 1.38629436111989061f;
    float rad = sqrtf(d2max);

    out[(size_t)(b * N + g) * 2 + 0] = make_float4(px, py, s, rad);
    out[(size_t)(b * N + g) * 2 + 1] = make_float4(col[g * 3 + 0], col[g * 3 + 1], col[g * 3 + 2], l);
}

__global__ void zero_kernel(float* __restrict__ p, int n) {
    int i = blockIdx.x * blockDim.x + threadIdx.x;
    if (i < n) p[i] = 0.0f;
}

__global__ __launch_bounds__(256) void accum_kernel(const float4* __restrict__ gdata,
                                                    float* __restrict__ accbuf,
                                                    int N, int gpb) {
    __shared__ float4 shc[CHUNK_G * 2];   // compacted: (px,py,s,l),(r,g,b,2s)
    __shared__ int wcnt[4];
    int gs   = blockIdx.x;          // gaussian split  (fastest -> XCD balance)
    int tile = blockIdx.y;          // 8 row-tiles of 16 rows
    int b    = blockIdx.z;          // camera
    int tid  = threadIdx.x;
    int x    = tid & 127;
    int yrow = tid >> 7;            // 0 or 1
    int ytop = tile * TILE_ROWS;
    int wid  = tid >> 6;
    int lane = tid & 63;

    float xf  = (float)x;
    float ylo = (float)ytop;
    float yhi = (float)(ytop + TILE_ROWS - 1);
    float y0f = (float)(ytop + yrow);

    float nr[PPT], ng[PPT], nb[PPT], nd[PPT];
#pragma unroll
    for (int p = 0; p < PPT; ++p) { nr[p] = 0.0f; ng[p] = 0.0f; nb[p] = 0.0f; nd[p] = 0.0f; }

    const float4* gbase = gdata + (size_t)b * N * 2;
    int g0 = gs * gpb;

    for (int cb = 0; cb < gpb; cb += CHUNK_G) {
        // ---- thread-parallel cull: one gaussian per thread (coalesced 32B) ----
        int src = (g0 + cb + tid) * 2;
        float4 f0 = gbase[src];        // px, py, s, rad
        float4 f1 = gbase[src + 1];    // r, g, b, l
        float px = f0.x, py = f0.y, rad = f0.w;
        bool keep = (py + rad >= ylo) & (py - rad <= yhi) &
                    (px + rad >= 0.0f) & (px - rad <= 127.0f);
        unsigned long long m = __ballot(keep);

        __syncthreads();                       // prior dense loop done with shc/wcnt
        if (lane == 0) wcnt[wid] = __popcll(m);
        __syncthreads();                       // wcnt visible
        int base = 0;
        if (wid > 0) base += wcnt[0];
        if (wid > 1) base += wcnt[1];
        if (wid > 2) base += wcnt[2];
        int total = wcnt[0] + wcnt[1] + wcnt[2] + wcnt[3];
        int pos = base + __popcll(m & ((1ull << lane) - 1ull));
        if (keep) {
            shc[pos * 2]     = make_float4(f0.x, f0.y, f0.z, f1.w);        // px,py,s,l
            shc[pos * 2 + 1] = make_float4(f1.x, f1.y, f1.z, f0.z + f0.z); // r,g,b,2s
        }
        __syncthreads();                       // shc visible

        // ---- branch-free dense loop over survivors (broadcast LDS reads) ----
        for (int j = 0; j < total; ++j) {
            float4 a0 = shc[j * 2];
            float4 a1 = shc[j * 2 + 1];
            float s   = a0.z;
            float dx  = a0.x - xf;
            float sdx = s * dx;
            float lm  = __builtin_fmaf(-sdx, sdx, a0.w);   // l - sdx^2
            float sdy = s * (a0.y - y0f);
            float s2  = a1.w;                              // 2s
#pragma unroll
            for (int p = 0; p < PPT; ++p) {
                float e = __builtin_fmaf(-sdy, sdy, lm);
                float w = __builtin_amdgcn_exp2f(e);
                nr[p] = __builtin_fmaf(w, a1.x, nr[p]);
                ng[p] = __builtin_fmaf(w, a1.y, ng[p]);
                nb[p] = __builtin_fmaf(w, a1.z, nb[p]);
                nd[p] += w;
                sdy -= s2;
            }
        }
    }

    float* ab = accbuf + (size_t)b * HWP * 4;
#pragma unroll
    for (int p = 0; p < PPT; ++p) {
        int y = ytop + yrow + p * 2;
        int pix = y * WW + x;
        atomicAdd(ab + pix * 4 + 0, nr[p]);
        atomicAdd(ab + pix * 4 + 1, ng[p]);
        atomicAdd(ab + pix * 4 + 2, nb[p]);
        atomicAdd(ab + pix * 4 + 3, nd[p]);
    }
}

__global__ void final_kernel(const float* __restrict__ accbuf,
                             float* __restrict__ out, int B, float epsadd) {
    int i = blockIdx.x * blockDim.x + threadIdx.x;   // over B*HW
    if (i >= B * HWP) return;
    int b = i / HWP;
    int p = i - b * HWP;
    const float* a = accbuf + (size_t)i * 4;
    float den = fmaxf(a[3] + epsadd, 1e-8f);
    out[(size_t)(b * 3 + 0) * HWP + p] = a[0] / den;
    out[(size_t)(b * 3 + 1) * HWP + p] = a[1] / den;
    out[(size_t)(b * 3 + 2) * HWP + p] = a[2] / den;
}

extern "C" void kernel_launch(void* const* d_in, const int* in_sizes, int n_in,
                              void* d_out, int out_size, void* d_ws, size_t ws_size,
                              hipStream_t stream) {
    const float* pos = (const float*)d_in[0];
    const float* col = (const float*)d_in[1];
    const float* opa = (const float*)d_in[2];
    const float* scl = (const float*)d_in[3];
    const float* qv  = (const float*)d_in[4];
    const float* tv  = (const float*)d_in[5];
    const float* fx  = (const float*)d_in[6];
    const float* fy  = (const float*)d_in[7];
    const float* cx  = (const float*)d_in[8];
    const float* cy  = (const float*)d_in[9];

    int N = in_sizes[0] / 3;
    int B = in_sizes[4] / 4;

    float4* proj   = (float4*)d_ws;
    float*  accbuf = (float*)((char*)d_ws + (size_t)B * N * 2 * sizeof(float4));
    float*  outp   = (float*)d_out;

    int tot = N * B;
    proj_kernel<<<(tot + 255) / 256, 256, 0, stream>>>(pos, col, opa, scl, qv, tv,
                                                       fx, fy, cx, cy, proj, N, B);

    int accn = B * HWP * 4;
    zero_kernel<<<(accn + 255) / 256, 256, 0, stream>>>(accbuf, accn);

    int gpb = N / GSPLIT;   // 512 gaussians per block
    dim3 grid(GSPLIT, HH / TILE_ROWS, B);   // x = gs  ->  each XCD sees all tiles
    accum_kernel<<<grid, 256, 0, stream>>>(proj, accbuf, N, gpb);

    float epsadd = (float)(N / 2048) * 1e-8f;  // reference adds EPS once per 2048-chunk
    final_kernel<<<(B * HWP + 255) / 256, 256, 0, stream>>>(accbuf, outp, B, epsadd);
}